// Round 4
// baseline (540.667 us; speedup 1.0000x reference)
//
#include <hip/hip_runtime.h>
#include <hip/hip_bf16.h>

#define B_ 128
#define T_ 512
#define N_ 256
#define H_ 1024

typedef unsigned short u16;
typedef __attribute__((ext_vector_type(8))) __bf16 bf16x8;
typedef __attribute__((ext_vector_type(4))) float f32x4;

__device__ __forceinline__ u16 f2bf(float f) {
    unsigned u = __float_as_uint(f);
    u = (u + 0x7FFFu + ((u >> 16) & 1u)) >> 16;
    return (u16)u;
}

__device__ __forceinline__ void g2l16(const void* g, void* l) {
    __builtin_amdgcn_global_load_lds(
        (const __attribute__((address_space(1))) void*)g,
        (__attribute__((address_space(3))) void*)l,
        16, 0, 0);
}

// ===========================================================================
// 256x256-tile 8-wave phase-pipelined GEMM (T1+T2+T3+T4+T5).
// R4: removed all sched_barrier(0) order-pins (m141 lesson) — plain s_barrier
// lets the compiler hoist next-phase ds_reads into the MFMA region.
// OUT: 0 = bf16 row-major, 1 = f32 row-major, 2 = bf16 transposed q-write.
// ===========================================================================
#define LBUF 32768u
#define LMAT 16384u
#define LKS  8192u

#define BAR() { __builtin_amdgcn_s_barrier(); }
#define GATE(N) { asm volatile("s_waitcnt vmcnt(" #N ")" ::: "memory"); \
                  __builtin_amdgcn_s_barrier(); }
#define LD4(dst, base) { _Pragma("unroll") for (int i_ = 0; i_ < 4; ++i_) \
    dst[i_] = *(const bf16x8*)(L + (base) + i_ * 512); }
#define MF16(MB, RA, RB) { __builtin_amdgcn_s_setprio(1); \
    _Pragma("unroll") for (int mi_ = 0; mi_ < 4; ++mi_) \
    _Pragma("unroll") for (int ni_ = 0; ni_ < 4; ++ni_) \
        acc[(MB) + mi_][ni_] = __builtin_amdgcn_mfma_f32_16x16x32_bf16( \
            RA[mi_], RB[ni_], acc[(MB) + mi_][ni_], 0, 0, 0); \
    __builtin_amdgcn_s_setprio(0); }

template<int ACT, int OUT>
__global__ __launch_bounds__(512, 2) void gemm256(
    const u16* __restrict__ A, const u16* __restrict__ Bt,
    float* __restrict__ Cf, u16* __restrict__ Cb,
    const float* __restrict__ bias,
    int Nc, int K, int bshift, int gysh)
{
    __shared__ u16 L[65536];
    const int tid = threadIdx.x;
    const int wave = tid >> 6, lane = tid & 63;
    const int l16 = lane & 15, lh = lane >> 4;
    const int wm = wave >> 2, wn = wave & 3;

    const int qq = (int)gridDim.x >> 3;
    const int orig = (int)blockIdx.x;
    const int wg = (orig & 7) * qq + (orig >> 3);
    const int by = wg & ((1 << gysh) - 1), bx = wg >> gysh;
    const size_t m0 = (size_t)bx * 256, n0 = (size_t)by * 256;

    const int sx8 = (lh ^ ((l16 >> 1) & 3)) * 8;
    const unsigned aoff = (unsigned)(wm * 4096 + l16 * 32 + sx8);
    const unsigned boff = (unsigned)(LMAT + wn * 2048 + l16 * 32 + sx8);

    const int srow = tid >> 2;
    const int sslot = (tid & 3) ^ ((srow >> 1) & 3);
    const size_t jstr = (size_t)128 * K;
    const u16* gA = A + (m0 + srow) * (size_t)K + sslot * 8;
    const u16* gB = Bt + (n0 + srow) * (size_t)K + sslot * 8;
    u16* const dA0 = L + (unsigned)(wave * 512);
    u16* const dB0 = L + LMAT + (unsigned)(wave * 512);

    f32x4 acc[8][4] = {};
    const int nt = K >> 6;

    g2l16(gA, dA0);             g2l16(gA + jstr, dA0 + 4096);
    g2l16(gB, dB0);             g2l16(gB + jstr, dB0 + 4096);
    g2l16(gA + 32, dA0 + LKS);  g2l16(gA + 32 + jstr, dA0 + LKS + 4096);
    g2l16(gB + 32, dB0 + LKS);  g2l16(gB + 32 + jstr, dB0 + LKS + 4096);
    GATE(4);

    for (int t = 0; t < nt - 1; ++t) {
        const unsigned ab = (t & 1) ? LBUF : 0u;
        const unsigned an = ab ^ LBUF;
        const u16* gAt = gA + (size_t)(t + 1) * 64;
        const u16* gBt = gB + (size_t)(t + 1) * 64;
        bf16x8 ra[4], ra2[4], rb0r[4], rb1r[4];
        LD4(ra,   ab + aoff);
        LD4(rb0r, ab + boff);
        g2l16(gAt, dA0 + an);  g2l16(gAt + jstr, dA0 + an + 4096);
        BAR();
        MF16(0, ra, rb0r);
        BAR();
        LD4(ra2, ab + aoff + 2048);
        g2l16(gBt, dB0 + an);  g2l16(gBt + jstr, dB0 + an + 4096);
        BAR();
        MF16(4, ra2, rb0r);
        GATE(4);
        LD4(ra,   ab + LKS + aoff);
        LD4(rb1r, ab + LKS + boff);
        g2l16(gAt + 32, dA0 + an + LKS);  g2l16(gAt + 32 + jstr, dA0 + an + LKS + 4096);
        BAR();
        MF16(0, ra, rb1r);
        BAR();
        LD4(ra2, ab + LKS + aoff + 2048);
        g2l16(gBt + 32, dB0 + an + LKS);  g2l16(gBt + 32 + jstr, dB0 + an + LKS + 4096);
        BAR();
        MF16(4, ra2, rb1r);
        GATE(4);
    }

    {
        const unsigned ab = ((nt - 1) & 1) ? LBUF : 0u;
        bf16x8 ra[4], ra2[4], rb0r[4], rb1r[4];
        LD4(ra,   ab + aoff);
        LD4(rb0r, ab + boff);
        BAR();
        MF16(0, ra, rb0r);
        BAR();
        LD4(ra2, ab + aoff + 2048);
        BAR();
        MF16(4, ra2, rb0r);
        GATE(0);
        LD4(ra,   ab + LKS + aoff);
        LD4(rb1r, ab + LKS + boff);
        BAR();
        MF16(0, ra, rb1r);
        BAR();
        LD4(ra2, ab + LKS + aoff + 2048);
        BAR();
        MF16(4, ra2, rb1r);
    }

    const size_t NcS = (size_t)Nc;
#pragma unroll
    for (int mi = 0; mi < 8; ++mi) {
#pragma unroll
        for (int ni = 0; ni < 4; ++ni) {
            size_t rbase = m0 + wm * 128 + mi * 16 + lh * 4;
            size_t col   = n0 + wn * 64 + ni * 16 + l16;
            if (OUT == 2) {
                u16 e[4];
#pragma unroll
                for (int rr = 0; rr < 4; ++rr) {
                    float v = acc[mi][ni][rr];
                    v = 1.0f / (1.0f + __expf(-v));
                    e[rr] = f2bf(v);
                }
                size_t qi = ((rbase >> 8) * (size_t)T_ + col) * N_ + (rbase & 255);
                *(uint2*)(Cb + qi) = *(const uint2*)e;
            } else {
#pragma unroll
                for (int rr = 0; rr < 4; ++rr) {
                    size_t row = rbase + rr;
                    float v = acc[mi][ni][rr];
                    if (bias) v += bias[(row >> bshift) * NcS + col];
                    if (ACT) v = 1.0f / (1.0f + __expf(-v));
                    if (OUT == 1) Cf[row * NcS + col] = v;
                    else          Cb[row * NcS + col] = f2bf(v);
                }
            }
        }
    }
}

// ---------------------------------------------------------------------------
// 128x128 2-barrier GEMM for the small prep GEMMs.
// C = act( (A @ Bt^T) * kscale + bmul * bias )
// ---------------------------------------------------------------------------
template<int ACT, int OUTF32>
__global__ __launch_bounds__(256) void gemm_bt(
    const u16* __restrict__ A, const u16* __restrict__ Bt,
    float* __restrict__ Cf, u16* __restrict__ Cb,
    const float* __restrict__ bias,
    int M, int Nc, int K, int bshift, float kscale, float bmul)
{
    __shared__ u16 lA[128 * 64];
    __shared__ u16 lB[128 * 64];
    const int tid = threadIdx.x;
    const int wave = tid >> 6, lane = tid & 63;
    const int l16 = lane & 15, lh = lane >> 4;
    const int wm = wave >> 1, wn = wave & 1;
    const long m0 = (long)blockIdx.x * 128;
    const long n0 = (long)blockIdx.y * 128;

    f32x4 acc[4][4] = {};

    for (int k0 = 0; k0 < K; k0 += 64) {
#pragma unroll
        for (int j = 0; j < 4; ++j) {
            int c = j * 256 + tid;
            int row = c >> 3, col = (c & 7) << 3;
            g2l16(A  + (m0 + row) * (size_t)K + k0 + col, &lA[(size_t)(j * 256 + (wave << 6)) * 8]);
            g2l16(Bt + (n0 + row) * (size_t)K + k0 + col, &lB[(size_t)(j * 256 + (wave << 6)) * 8]);
        }
        __syncthreads();
#pragma unroll
        for (int s = 0; s < 2; ++s) {
            bf16x8 af[4], bfr[4];
#pragma unroll
            for (int mi = 0; mi < 4; ++mi)
                af[mi] = *(const bf16x8*)&lA[((wm << 6) + (mi << 4) + l16) * 64 + s * 32 + (lh << 3)];
#pragma unroll
            for (int ni = 0; ni < 4; ++ni)
                bfr[ni] = *(const bf16x8*)&lB[((wn << 6) + (ni << 4) + l16) * 64 + s * 32 + (lh << 3)];
#pragma unroll
            for (int mi = 0; mi < 4; ++mi)
#pragma unroll
                for (int ni = 0; ni < 4; ++ni)
                    acc[mi][ni] = __builtin_amdgcn_mfma_f32_16x16x32_bf16(af[mi], bfr[ni], acc[mi][ni], 0, 0, 0);
        }
        __syncthreads();
    }

#pragma unroll
    for (int mi = 0; mi < 4; ++mi) {
#pragma unroll
        for (int ni = 0; ni < 4; ++ni) {
            long rbase = m0 + (wm << 6) + (mi << 4) + (lh << 2);
            long col   = n0 + (wn << 6) + (ni << 4) + l16;
#pragma unroll
            for (int r = 0; r < 4; ++r) {
                long row = rbase + r;
                float v = acc[mi][ni][r] * kscale;
                if (bias) v += bmul * bias[(size_t)(row >> bshift) * Nc + col];
                if (ACT) v = 1.0f / (1.0f + __expf(-v));
                if (OUTF32) Cf[(size_t)row * Nc + col] = v;
                else        Cb[(size_t)row * Nc + col] = f2bf(v);
            }
        }
    }
}

// x[B,T,N] f32 -> h[B,N,T] bf16 transpose + per-(b,t) rowsum (fused, one x read)
__global__ __launch_bounds__(256) void k_trx_rs(
    const float* __restrict__ x, u16* __restrict__ h, u16* __restrict__ s1b)
{
    __shared__ float sm[32][257];
    const int b = blockIdx.y, t0 = blockIdx.x * 32;
    const int tid = threadIdx.x;
    const float* xb = x + ((size_t)b * T_ + t0) * N_;
#pragma unroll 8
    for (int j = 0; j < 32; ++j)
        sm[j][tid] = xb[(size_t)j * N_ + tid];
    __syncthreads();
    const int wave = tid >> 6, lane = tid & 63;
#pragma unroll
    for (int i = 0; i < 8; ++i) {
        int j = wave * 8 + i;
        float s = sm[j][lane] + sm[j][lane + 64] + sm[j][lane + 128] + sm[j][lane + 192];
#pragma unroll
        for (int o = 32; o; o >>= 1) s += __shfl_down(s, o, 64);
        if (lane == 0) s1b[(size_t)b * T_ + t0 + j] = f2bf(s);
    }
    u16 e[32];
#pragma unroll
    for (int j = 0; j < 32; ++j) e[j] = f2bf(sm[j][tid]);
    uint4* dst = (uint4*)(h + ((size_t)b * N_ + tid) * T_ + t0);
    const uint4* src = (const uint4*)e;
#pragma unroll
    for (int v = 0; v < 4; ++v) dst[v] = src[v];
}

// Wl1,Wr1 [512,1024] -> W1t=(Wr1-Wl1/255)^T, Wl1t=Wl1^T, Wlr1t=(Wl1+Wr1)^T  [1024,512]
__global__ void k_tr3(const float* __restrict__ Wl, const float* __restrict__ Wr,
                      u16* __restrict__ W1t, u16* __restrict__ Wl1t, u16* __restrict__ Wlr1t)
{
    __shared__ float tl[32][33], tr[32][33];
    int r0 = blockIdx.x * 32, c0 = blockIdx.y * 32;
    int tx = threadIdx.x, ty = threadIdx.y;
#pragma unroll
    for (int i = 0; i < 4; ++i) {
        int r = r0 + ty + 8 * i;
        tl[ty + 8 * i][tx] = Wl[(size_t)r * H_ + c0 + tx];
        tr[ty + 8 * i][tx] = Wr[(size_t)r * H_ + c0 + tx];
    }
    __syncthreads();
#pragma unroll
    for (int i = 0; i < 4; ++i) {
        int c = c0 + ty + 8 * i;
        float wl = tl[tx][ty + 8 * i], wr = tr[tx][ty + 8 * i];
        size_t o = (size_t)c * T_ + r0 + tx;
        W1t[o]   = f2bf(wr - wl * (1.0f / 255.0f));
        Wl1t[o]  = f2bf(wl);
        Wlr1t[o] = f2bf(wl + wr);
    }
}

// Wl2,Wr2 [1024,1024] -> W2t=(Wr2-Wl2/255)^T, Wl2t=Wl2^T  [1024,1024]
__global__ void k_tr2(const float* __restrict__ Wl, const float* __restrict__ Wr,
                      u16* __restrict__ W2t, u16* __restrict__ Wl2t)
{
    __shared__ float tl[32][33], tr[32][33];
    int r0 = blockIdx.x * 32, c0 = blockIdx.y * 32;
    int tx = threadIdx.x, ty = threadIdx.y;
#pragma unroll
    for (int i = 0; i < 4; ++i) {
        int r = r0 + ty + 8 * i;
        tl[ty + 8 * i][tx] = Wl[(size_t)r * H_ + c0 + tx];
        tr[ty + 8 * i][tx] = Wr[(size_t)r * H_ + c0 + tx];
    }
    __syncthreads();
#pragma unroll
    for (int i = 0; i < 4; ++i) {
        int c = c0 + ty + 8 * i;
        float wl = tl[tx][ty + 8 * i], wr = tr[tx][ty + 8 * i];
        size_t o = (size_t)c * H_ + r0 + tx;
        W2t[o]  = f2bf(wr - wl * (1.0f / 255.0f));
        Wl2t[o] = f2bf(wl);
    }
}

// Wt[c][r] = bf16(W[r][c])
__global__ void k_trc(const float* __restrict__ W, u16* __restrict__ Wt, int R, int C) {
    __shared__ float tile[32][33];
    int r0 = blockIdx.x * 32, c0 = blockIdx.y * 32;
    int tx = threadIdx.x, ty = threadIdx.y;
#pragma unroll
    for (int i = 0; i < 4; ++i)
        tile[ty + 8 * i][tx] = W[(size_t)(r0 + ty + 8 * i) * C + c0 + tx];
    __syncthreads();
#pragma unroll
    for (int i = 0; i < 4; ++i)
        Wt[(size_t)(c0 + ty + 8 * i) * R + r0 + tx] = f2bf(tile[tx][ty + 8 * i]);
}

// f32 -> bf16 cast, 8 elems/thread
__global__ void k_cast(const float* __restrict__ s, u16* __restrict__ d, int n8) {
    int i = blockIdx.x * 256 + threadIdx.x;
    if (i < n8) {
        float4 a = ((const float4*)s)[2 * i], b = ((const float4*)s)[2 * i + 1];
        u16 e[8] = {f2bf(a.x), f2bf(a.y), f2bf(a.z), f2bf(a.w),
                    f2bf(b.x), f2bf(b.y), f2bf(b.z), f2bf(b.w)};
        ((uint4*)d)[i] = *(const uint4*)e;
    }
}

extern "C" void kernel_launch(void* const* d_in, const int* in_sizes, int n_in,
                              void* d_out, int out_size, void* d_ws, size_t ws_size,
                              hipStream_t stream)
{
    const float* x   = (const float*)d_in[0];
    const float* Wl1 = (const float*)d_in[1];
    const float* Wr1 = (const float*)d_in[2];
    const float* b1  = (const float*)d_in[3];
    const float* Wl2 = (const float*)d_in[4];
    const float* Wr2 = (const float*)d_in[5];
    const float* b2  = (const float*)d_in[6];
    const float* W1a = (const float*)d_in[7];
    const float* W1b = (const float*)d_in[8];
    const float* W2a = (const float*)d_in[9];
    const float* W2b = (const float*)d_in[10];
    float* out = (float*)d_out;

    char* ws = (char*)d_ws;
    size_t off = 0;
    auto alloc = [&](size_t bytes) -> char* {
        char* p = ws + off;
        off += (bytes + 255) & ~(size_t)255;
        return p;
    };

    const size_t BN = (size_t)B_ * N_;   // 32768
    const size_t BT = (size_t)B_ * T_;   // 65536

    u16* h_bf   = (u16*)alloc(BN * T_ * 2);
    u16* h1_bf  = (u16*)alloc(BN * H_ * 2);
    u16* h2_bf  = (u16*)alloc(BN * H_ * 2);
    u16* W1t    = (u16*)alloc((size_t)H_ * T_ * 2);
    u16* Wl1t   = (u16*)alloc((size_t)H_ * T_ * 2);
    u16* Wlr1t  = (u16*)alloc((size_t)H_ * T_ * 2);
    u16* W2t    = (u16*)alloc((size_t)H_ * H_ * 2);
    u16* Wl2t   = (u16*)alloc((size_t)H_ * H_ * 2);
    u16* W1bt   = (u16*)alloc((size_t)T_ * H_ * 2);
    u16* W1ab   = (u16*)alloc((size_t)H_ * H_ * 2);
    u16* W1ct   = (u16*)alloc((size_t)T_ * H_ * 2);
    u16* W2bt   = (u16*)alloc((size_t)H_ * N_ * 2);
    u16* W2ab   = (u16*)alloc((size_t)N_ * N_ * 2);
    u16* W2ct   = (u16*)alloc((size_t)H_ * N_ * 2);
    u16* s1b    = (u16*)alloc(BT * 2);
    float* t1b1 = (float*)alloc((size_t)B_ * H_ * 4);
    float* t2b2 = (float*)alloc((size_t)B_ * H_ * 4);
    u16*   u1s  = (u16*)alloc((size_t)B_ * H_ * 2);

    u16* q_bf = h_bf;

    dim3 blk32(32, 8);

    // --- prep ---
    k_trx_rs<<<dim3(T_ / 32, B_), 256, 0, stream>>>(x, h_bf, s1b);
    k_tr3<<<dim3(T_ / 32, H_ / 32), blk32, 0, stream>>>(Wl1, Wr1, W1t, Wl1t, Wlr1t);
    k_tr2<<<dim3(H_ / 32, H_ / 32), blk32, 0, stream>>>(Wl2, Wr2, W2t, Wl2t);
    k_trc<<<dim3(H_ / 32, T_ / 32), blk32, 0, stream>>>(W1b, W1bt, H_, T_);
    k_trc<<<dim3(N_ / 32, H_ / 32), blk32, 0, stream>>>(W2b, W2bt, N_, H_);
    k_cast<<<dim3(H_ * H_ / 2048), 256, 0, stream>>>(W1a, W1ab, H_ * H_ / 8);
    k_cast<<<dim3(N_ * N_ / 2048), 256, 0, stream>>>(W2a, W2ab, N_ * N_ / 8);

    gemm_bt<0, 1><<<dim3(1, H_ / 128), 256, 0, stream>>>(s1b, Wl1t,  t1b1, nullptr, b1, B_, H_, T_, 31, 1.0f / 255.0f, 1.0f);
    gemm_bt<0, 0><<<dim3(1, H_ / 128), 256, 0, stream>>>(s1b, Wlr1t, nullptr, u1s,  b1, B_, H_, T_, 31, 1.0f / 255.0f, 256.0f / 255.0f);
    gemm_bt<0, 1><<<dim3(1, H_ / 128), 256, 0, stream>>>(u1s, Wl2t, t2b2, nullptr, b2, B_, H_, H_, 31, 1.0f, 1.0f);
    gemm_bt<0, 0><<<dim3(T_ / 128, H_ / 128), 256, 0, stream>>>(W1bt, W1ab, nullptr, W1ct, nullptr, T_, H_, H_, 0, 1.0f, 0.0f);
    gemm_bt<0, 0><<<dim3(H_ / 128, N_ / 128), 256, 0, stream>>>(W2bt, W2ab, nullptr, W2ct, nullptr, H_, N_, N_, 0, 1.0f, 0.0f);

    // --- main chain ---
    gemm256<0, 0><<<dim3(128 * 4), 512, 0, stream>>>(h_bf, W1t, nullptr, h1_bf, t1b1, H_, T_, 8, 2);
    gemm256<0, 0><<<dim3(128 * 4), 512, 0, stream>>>(h1_bf, W2t, nullptr, h2_bf, t2b2, H_, H_, 8, 2);
    gemm256<1, 2><<<dim3(128 * 2), 512, 0, stream>>>(h2_bf, W1ct, nullptr, q_bf, nullptr, T_, H_, 0, 1);
    gemm256<1, 1><<<dim3(256 * 4), 512, 0, stream>>>(q_bf, W2ct, out, nullptr, nullptr, H_, N_, 0, 2);
}

// Round 5
// 477.394 us; speedup vs baseline: 1.1325x; 1.1325x over previous
//
#include <hip/hip_runtime.h>
#include <hip/hip_bf16.h>

#define B_ 128
#define T_ 512
#define N_ 256
#define H_ 1024

typedef unsigned short u16;
typedef __attribute__((ext_vector_type(8))) __bf16 bf16x8;
typedef __attribute__((ext_vector_type(4))) float f32x4;

__device__ __forceinline__ u16 f2bf(float f) {
    unsigned u = __float_as_uint(f);
    u = (u + 0x7FFFu + ((u >> 16) & 1u)) >> 16;
    return (u16)u;
}

__device__ __forceinline__ void g2l16(const void* g, void* l) {
    __builtin_amdgcn_global_load_lds(
        (const __attribute__((address_space(1))) void*)g,
        (__attribute__((address_space(3))) void*)l,
        16, 0, 0);
}

// ===========================================================================
// 256x256-tile 8-wave phase-pipelined GEMM with counted vmcnt.
// R5: #pragma unroll 1 on K-loop (register-liveness insurance).
// OUT: 0 = bf16 row-major, 1 = f32 row-major, 2 = bf16 transposed q-write.
// ===========================================================================
#define LBUF 32768u
#define LMAT 16384u
#define LKS  8192u

#define BAR() { __builtin_amdgcn_s_barrier(); }
#define GATE(N) { asm volatile("s_waitcnt vmcnt(" #N ")" ::: "memory"); \
                  __builtin_amdgcn_s_barrier(); }
#define LD4(dst, base) { _Pragma("unroll") for (int i_ = 0; i_ < 4; ++i_) \
    dst[i_] = *(const bf16x8*)(L + (base) + i_ * 512); }
#define MF16(MB, RA, RB) { __builtin_amdgcn_s_setprio(1); \
    _Pragma("unroll") for (int mi_ = 0; mi_ < 4; ++mi_) \
    _Pragma("unroll") for (int ni_ = 0; ni_ < 4; ++ni_) \
        acc[(MB) + mi_][ni_] = __builtin_amdgcn_mfma_f32_16x16x32_bf16( \
            RA[mi_], RB[ni_], acc[(MB) + mi_][ni_], 0, 0, 0); \
    __builtin_amdgcn_s_setprio(0); }

template<int ACT, int OUT>
__global__ __launch_bounds__(512, 2) void gemm256(
    const u16* __restrict__ A, const u16* __restrict__ Bt,
    float* __restrict__ Cf, u16* __restrict__ Cb,
    const float* __restrict__ bias,
    int Nc, int K, int bshift, int gysh)
{
    __shared__ u16 L[65536];
    const int tid = threadIdx.x;
    const int wave = tid >> 6, lane = tid & 63;
    const int l16 = lane & 15, lh = lane >> 4;
    const int wm = wave >> 2, wn = wave & 3;

    const int qq = (int)gridDim.x >> 3;
    const int orig = (int)blockIdx.x;
    const int wg = (orig & 7) * qq + (orig >> 3);
    const int by = wg & ((1 << gysh) - 1), bx = wg >> gysh;
    const size_t m0 = (size_t)bx * 256, n0 = (size_t)by * 256;

    const int sx8 = (lh ^ ((l16 >> 1) & 3)) * 8;
    const unsigned aoff = (unsigned)(wm * 4096 + l16 * 32 + sx8);
    const unsigned boff = (unsigned)(LMAT + wn * 2048 + l16 * 32 + sx8);

    const int srow = tid >> 2;
    const int sslot = (tid & 3) ^ ((srow >> 1) & 3);
    const size_t jstr = (size_t)128 * K;
    const u16* gA = A + (m0 + srow) * (size_t)K + sslot * 8;
    const u16* gB = Bt + (n0 + srow) * (size_t)K + sslot * 8;
    u16* const dA0 = L + (unsigned)(wave * 512);
    u16* const dB0 = L + LMAT + (unsigned)(wave * 512);

    f32x4 acc[8][4] = {};
    const int nt = K >> 6;

    g2l16(gA, dA0);             g2l16(gA + jstr, dA0 + 4096);
    g2l16(gB, dB0);             g2l16(gB + jstr, dB0 + 4096);
    g2l16(gA + 32, dA0 + LKS);  g2l16(gA + 32 + jstr, dA0 + LKS + 4096);
    g2l16(gB + 32, dB0 + LKS);  g2l16(gB + 32 + jstr, dB0 + LKS + 4096);
    GATE(4);

#pragma unroll 1
    for (int t = 0; t < nt - 1; ++t) {
        const unsigned ab = (t & 1) ? LBUF : 0u;
        const unsigned an = ab ^ LBUF;
        const u16* gAt = gA + (size_t)(t + 1) * 64;
        const u16* gBt = gB + (size_t)(t + 1) * 64;
        bf16x8 ra[4], ra2[4], rb0r[4], rb1r[4];
        LD4(ra,   ab + aoff);
        LD4(rb0r, ab + boff);
        g2l16(gAt, dA0 + an);  g2l16(gAt + jstr, dA0 + an + 4096);
        BAR();
        MF16(0, ra, rb0r);
        BAR();
        LD4(ra2, ab + aoff + 2048);
        g2l16(gBt, dB0 + an);  g2l16(gBt + jstr, dB0 + an + 4096);
        BAR();
        MF16(4, ra2, rb0r);
        GATE(4);
        LD4(ra,   ab + LKS + aoff);
        LD4(rb1r, ab + LKS + boff);
        g2l16(gAt + 32, dA0 + an + LKS);  g2l16(gAt + 32 + jstr, dA0 + an + LKS + 4096);
        BAR();
        MF16(0, ra, rb1r);
        BAR();
        LD4(ra2, ab + LKS + aoff + 2048);
        g2l16(gBt + 32, dB0 + an + LKS);  g2l16(gBt + 32 + jstr, dB0 + an + LKS + 4096);
        BAR();
        MF16(4, ra2, rb1r);
        GATE(4);
    }

    {
        const unsigned ab = ((nt - 1) & 1) ? LBUF : 0u;
        bf16x8 ra[4], ra2[4], rb0r[4], rb1r[4];
        LD4(ra,   ab + aoff);
        LD4(rb0r, ab + boff);
        BAR();
        MF16(0, ra, rb0r);
        BAR();
        LD4(ra2, ab + aoff + 2048);
        BAR();
        MF16(4, ra2, rb0r);
        GATE(0);
        LD4(ra,   ab + LKS + aoff);
        LD4(rb1r, ab + LKS + boff);
        BAR();
        MF16(0, ra, rb1r);
        BAR();
        LD4(ra2, ab + LKS + aoff + 2048);
        BAR();
        MF16(4, ra2, rb1r);
    }

    const size_t NcS = (size_t)Nc;
#pragma unroll
    for (int mi = 0; mi < 8; ++mi) {
#pragma unroll
        for (int ni = 0; ni < 4; ++ni) {
            size_t rbase = m0 + wm * 128 + mi * 16 + lh * 4;
            size_t col   = n0 + wn * 64 + ni * 16 + l16;
            if (OUT == 2) {
                u16 e[4];
#pragma unroll
                for (int rr = 0; rr < 4; ++rr) {
                    float v = acc[mi][ni][rr];
                    v = 1.0f / (1.0f + __expf(-v));
                    e[rr] = f2bf(v);
                }
                size_t qi = ((rbase >> 8) * (size_t)T_ + col) * N_ + (rbase & 255);
                *(uint2*)(Cb + qi) = *(const uint2*)e;
            } else {
#pragma unroll
                for (int rr = 0; rr < 4; ++rr) {
                    size_t row = rbase + rr;
                    float v = acc[mi][ni][rr];
                    if (bias) v += bias[(row >> bshift) * NcS + col];
                    if (ACT) v = 1.0f / (1.0f + __expf(-v));
                    if (OUT == 1) Cf[row * NcS + col] = v;
                    else          Cb[row * NcS + col] = f2bf(v);
                }
            }
        }
    }
}

// ---------------------------------------------------------------------------
// 128x128 2-barrier GEMM for small prep GEMMs.
// C = act( (A @ Bt^T) * kscale + bmul * bias )
// DUAL=1: Nc=2048; col<1024 -> Cb[row*1024+col] (+1.0*b[col]);
//         col>=1024 -> ((u16*)Cf)[row*1024+col-1024] (+256/255*b[col&1023]).
// ---------------------------------------------------------------------------
template<int ACT, int OUTF32, int DUAL>
__global__ __launch_bounds__(256) void gemm_bt(
    const u16* __restrict__ A, const u16* __restrict__ Bt,
    float* __restrict__ Cf, u16* __restrict__ Cb,
    const float* __restrict__ bias,
    int M, int Nc, int K, int bshift, float kscale, float bmul)
{
    __shared__ u16 lA[128 * 64];
    __shared__ u16 lB[128 * 64];
    const int tid = threadIdx.x;
    const int wave = tid >> 6, lane = tid & 63;
    const int l16 = lane & 15, lh = lane >> 4;
    const int wm = wave >> 1, wn = wave & 1;
    const long m0 = (long)blockIdx.x * 128;
    const long n0 = (long)blockIdx.y * 128;

    f32x4 acc[4][4] = {};

    for (int k0 = 0; k0 < K; k0 += 64) {
#pragma unroll
        for (int j = 0; j < 4; ++j) {
            int c = j * 256 + tid;
            int row = c >> 3, col = (c & 7) << 3;
            g2l16(A  + (m0 + row) * (size_t)K + k0 + col, &lA[(size_t)(j * 256 + (wave << 6)) * 8]);
            g2l16(Bt + (n0 + row) * (size_t)K + k0 + col, &lB[(size_t)(j * 256 + (wave << 6)) * 8]);
        }
        __syncthreads();
#pragma unroll
        for (int s = 0; s < 2; ++s) {
            bf16x8 af[4], bfr[4];
#pragma unroll
            for (int mi = 0; mi < 4; ++mi)
                af[mi] = *(const bf16x8*)&lA[((wm << 6) + (mi << 4) + l16) * 64 + s * 32 + (lh << 3)];
#pragma unroll
            for (int ni = 0; ni < 4; ++ni)
                bfr[ni] = *(const bf16x8*)&lB[((wn << 6) + (ni << 4) + l16) * 64 + s * 32 + (lh << 3)];
#pragma unroll
            for (int mi = 0; mi < 4; ++mi)
#pragma unroll
                for (int ni = 0; ni < 4; ++ni)
                    acc[mi][ni] = __builtin_amdgcn_mfma_f32_16x16x32_bf16(af[mi], bfr[ni], acc[mi][ni], 0, 0, 0);
        }
        __syncthreads();
    }

#pragma unroll
    for (int mi = 0; mi < 4; ++mi) {
#pragma unroll
        for (int ni = 0; ni < 4; ++ni) {
            long rbase = m0 + (wm << 6) + (mi << 4) + (lh << 2);
            long col   = n0 + (wn << 6) + (ni << 4) + l16;
#pragma unroll
            for (int r = 0; r < 4; ++r) {
                long row = rbase + r;
                float v = acc[mi][ni][r] * kscale;
                if (DUAL) {
                    float bv = bias[col & 1023];
                    v += (col < 1024 ? 1.0f : 256.0f / 255.0f) * bv;
                    if (col < 1024) Cb[(size_t)row * 1024 + col] = f2bf(v);
                    else ((u16*)Cf)[(size_t)row * 1024 + (col - 1024)] = f2bf(v);
                } else {
                    if (bias) v += bmul * bias[(size_t)(row >> bshift) * Nc + col];
                    if (ACT) v = 1.0f / (1.0f + __expf(-v));
                    if (OUTF32) Cf[(size_t)row * Nc + col] = v;
                    else        Cb[(size_t)row * Nc + col] = f2bf(v);
                }
            }
        }
    }
}

// x[B,T,N] f32 -> h[B,N,T] bf16 transpose + per-(b,t) rowsum (one x read)
__global__ __launch_bounds__(256) void k_trx_rs(
    const float* __restrict__ x, u16* __restrict__ h, u16* __restrict__ s1b)
{
    __shared__ float sm[32][257];
    const int b = blockIdx.y, t0 = blockIdx.x * 32;
    const int tid = threadIdx.x;
    const float* xb = x + ((size_t)b * T_ + t0) * N_;
#pragma unroll 8
    for (int j = 0; j < 32; ++j)
        sm[j][tid] = xb[(size_t)j * N_ + tid];
    __syncthreads();
    const int wave = tid >> 6, lane = tid & 63;
#pragma unroll
    for (int i = 0; i < 8; ++i) {
        int j = wave * 8 + i;
        float s = sm[j][lane] + sm[j][lane + 64] + sm[j][lane + 128] + sm[j][lane + 192];
#pragma unroll
        for (int o = 32; o; o >>= 1) s += __shfl_down(s, o, 64);
        if (lane == 0) s1b[(size_t)b * T_ + t0 + j] = f2bf(s);
    }
    u16 e[32];
#pragma unroll
    for (int j = 0; j < 32; ++j) e[j] = f2bf(sm[j][tid]);
    uint4* dst = (uint4*)(h + ((size_t)b * N_ + tid) * T_ + t0);
    const uint4* src = (const uint4*)e;
#pragma unroll
    for (int v = 0; v < 4; ++v) dst[v] = src[v];
}

// Fused weight transposes (all 32x32-tiled), one launch:
// job A (512 blk): Wl1,Wr1[512,1024] -> Wl1t[c,r]=wl, Wlr1t[c,r]=wl+wr,
//                  W1rm[r,c]=wr-wl/255 (row-major)
// job B (1024):    Wl2,Wr2[1024,1024] -> W2t[c,r]=wr-wl/255, Wl2t[c,r]=wl
// job C (512):     W1b[1024,512] -> W1bt[512,1024]
// job D (256):     W2b[256,1024] -> W2bt[1024,256]
__global__ void k_wtr(const float* __restrict__ Wl1, const float* __restrict__ Wr1,
                      const float* __restrict__ Wl2, const float* __restrict__ Wr2,
                      const float* __restrict__ W1b, const float* __restrict__ W2b,
                      u16* __restrict__ Wl1t, u16* __restrict__ Wlr1t, u16* __restrict__ W1rm,
                      u16* __restrict__ W2t, u16* __restrict__ Wl2t,
                      u16* __restrict__ W1bt, u16* __restrict__ W2bt)
{
    __shared__ float tl[32][33], tr[32][33];
    int bid = blockIdx.x;
    const int tx = threadIdx.x, ty = threadIdx.y;
    if (bid < 512) {
        int r0 = (bid >> 5) * 32, c0 = (bid & 31) * 32;
#pragma unroll
        for (int i = 0; i < 4; ++i) {
            int r = r0 + ty + 8 * i;
            float wl = Wl1[(size_t)r * H_ + c0 + tx];
            float wr = Wr1[(size_t)r * H_ + c0 + tx];
            tl[ty + 8 * i][tx] = wl;
            tr[ty + 8 * i][tx] = wl + wr;
            W1rm[(size_t)r * H_ + c0 + tx] = f2bf(wr - wl * (1.0f / 255.0f));
        }
        __syncthreads();
#pragma unroll
        for (int i = 0; i < 4; ++i) {
            size_t o = (size_t)(c0 + ty + 8 * i) * T_ + r0 + tx;
            Wl1t[o]  = f2bf(tl[tx][ty + 8 * i]);
            Wlr1t[o] = f2bf(tr[tx][ty + 8 * i]);
        }
    } else if (bid < 1536) {
        bid -= 512;
        int r0 = (bid >> 5) * 32, c0 = (bid & 31) * 32;
#pragma unroll
        for (int i = 0; i < 4; ++i) {
            int r = r0 + ty + 8 * i;
            float wl = Wl2[(size_t)r * H_ + c0 + tx];
            float wr = Wr2[(size_t)r * H_ + c0 + tx];
            tl[ty + 8 * i][tx] = wr - wl * (1.0f / 255.0f);
            tr[ty + 8 * i][tx] = wl;
        }
        __syncthreads();
#pragma unroll
        for (int i = 0; i < 4; ++i) {
            size_t o = (size_t)(c0 + ty + 8 * i) * H_ + r0 + tx;
            W2t[o]  = f2bf(tl[tx][ty + 8 * i]);
            Wl2t[o] = f2bf(tr[tx][ty + 8 * i]);
        }
    } else if (bid < 2048) {
        bid -= 1536;
        int r0 = (bid >> 4) * 32, c0 = (bid & 15) * 32;
#pragma unroll
        for (int i = 0; i < 4; ++i)
            tl[ty + 8 * i][tx] = W1b[(size_t)(r0 + ty + 8 * i) * T_ + c0 + tx];
        __syncthreads();
#pragma unroll
        for (int i = 0; i < 4; ++i)
            W1bt[(size_t)(c0 + ty + 8 * i) * H_ + r0 + tx] = f2bf(tl[tx][ty + 8 * i]);
    } else {
        bid -= 2048;
        int r0 = (bid >> 5) * 32, c0 = (bid & 31) * 32;
#pragma unroll
        for (int i = 0; i < 4; ++i)
            tl[ty + 8 * i][tx] = W2b[(size_t)(r0 + ty + 8 * i) * H_ + c0 + tx];
        __syncthreads();
#pragma unroll
        for (int i = 0; i < 4; ++i)
            W2bt[(size_t)(c0 + ty + 8 * i) * N_ + r0 + tx] = f2bf(tl[tx][ty + 8 * i]);
    }
}

// Straight f32->bf16 casts: W1a (1024*1024) then W2a (256*256), 8 elems/thread.
__global__ void k_wcast(const float* __restrict__ W1a, const float* __restrict__ W2a,
                        u16* __restrict__ W1ab, u16* __restrict__ W2ab)
{
    int i = blockIdx.x * 256 + threadIdx.x;
    const int n1 = H_ * H_ / 8;          // 131072
    const int n2 = N_ * N_ / 8;          // 8192
    if (i >= n1 + n2) return;
    const float* s; u16* d;
    if (i < n1) { s = W1a; d = W1ab; }
    else        { s = W2a; d = W2ab; i -= n1; }
    float4 a = ((const float4*)s)[2 * i], b = ((const float4*)s)[2 * i + 1];
    u16 e[8] = {f2bf(a.x), f2bf(a.y), f2bf(a.z), f2bf(a.w),
                f2bf(b.x), f2bf(b.y), f2bf(b.z), f2bf(b.w)};
    ((uint4*)d)[i] = *(const uint4*)e;
}

extern "C" void kernel_launch(void* const* d_in, const int* in_sizes, int n_in,
                              void* d_out, int out_size, void* d_ws, size_t ws_size,
                              hipStream_t stream)
{
    const float* x   = (const float*)d_in[0];
    const float* Wl1 = (const float*)d_in[1];
    const float* Wr1 = (const float*)d_in[2];
    const float* b1  = (const float*)d_in[3];
    const float* Wl2 = (const float*)d_in[4];
    const float* Wr2 = (const float*)d_in[5];
    const float* b2  = (const float*)d_in[6];
    const float* W1a = (const float*)d_in[7];
    const float* W1b = (const float*)d_in[8];
    const float* W2a = (const float*)d_in[9];
    const float* W2b = (const float*)d_in[10];
    float* out = (float*)d_out;

    char* ws = (char*)d_ws;
    size_t off = 0;
    auto alloc = [&](size_t bytes) -> char* {
        char* p = ws + off;
        off += (bytes + 255) & ~(size_t)255;
        return p;
    };

    const size_t BN = (size_t)B_ * N_;   // 32768
    const size_t BT = (size_t)B_ * T_;   // 65536

    u16* h_bf   = (u16*)alloc(BN * T_ * 2);           // h, later q
    u16* h2_bf  = (u16*)alloc(BN * H_ * 2);
    u16* Wcat   = (u16*)alloc((size_t)H_ * T_ * 2 * 2); // [Wl1t ; Wlr1t], contiguous
    u16* W1rm   = (u16*)alloc((size_t)T_ * H_ * 2);
    u16* W2t    = (u16*)alloc((size_t)H_ * H_ * 2);
    u16* Wl2t   = (u16*)alloc((size_t)H_ * H_ * 2);
    u16* W1bt   = (u16*)alloc((size_t)T_ * H_ * 2);
    u16* W1ab   = (u16*)alloc((size_t)H_ * H_ * 2);
    u16* W1ct   = (u16*)alloc((size_t)T_ * H_ * 2);
    u16* W2bt   = (u16*)alloc((size_t)H_ * N_ * 2);
    u16* W2ab   = (u16*)alloc((size_t)N_ * N_ * 2);
    u16* W2ct   = (u16*)alloc((size_t)H_ * N_ * 2);
    u16* W12t   = (u16*)alloc((size_t)H_ * T_ * 2);
    u16* s1b    = (u16*)alloc(BT * 2);
    u16* t1b1b  = (u16*)alloc((size_t)B_ * H_ * 2);
    u16* u1s    = (u16*)alloc((size_t)B_ * H_ * 2);
    float* t2b2 = (float*)alloc((size_t)B_ * H_ * 4);
    float* t12  = (float*)alloc((size_t)B_ * H_ * 4);

    u16* Wl1t  = Wcat;
    u16* Wlr1t = Wcat + (size_t)H_ * T_;
    u16* q_bf  = h_bf;

    // --- prep ---
    k_trx_rs<<<dim3(T_ / 32, B_), 256, 0, stream>>>(x, h_bf, s1b);
    k_wtr<<<dim3(2304), dim3(32, 8), 0, stream>>>(Wl1, Wr1, Wl2, Wr2, W1b, W2b,
                                                  Wl1t, Wlr1t, W1rm, W2t, Wl2t, W1bt, W2bt);
    k_wcast<<<dim3(545), 256, 0, stream>>>(W1a, W2a, W1ab, W2ab);

    // S1: [t1b1b | u1s] = s1 @ [Wl1 | Wl1+Wr1] / 255 (+ b1 terms), dual bf16 out
    gemm_bt<0, 0, 1><<<dim3(1, 16), 256, 0, stream>>>(s1b, Wcat, (float*)u1s, t1b1b, b1,
                                                      B_, 2048, T_, 0, 1.0f / 255.0f, 1.0f);
    // S2: t2b2 = u1s @ Wl2 + b2   (f32)
    gemm_bt<0, 1, 0><<<dim3(1, H_ / 128), 256, 0, stream>>>(u1s, Wl2t, t2b2, nullptr, b2,
                                                            B_, H_, H_, 31, 1.0f, 1.0f);
    // S3: t12 = t1b1 @ W2' + t2b2 (f32, full-matrix bias, bshift=0)
    gemm_bt<0, 1, 0><<<dim3(1, H_ / 128), 256, 0, stream>>>(t1b1b, W2t, t12, nullptr, t2b2,
                                                            B_, H_, H_, 0, 1.0f, 1.0f);
    // P1: W12t = (W1' @ W2')^T : A=W2t, Bt=W1rm, M=1024, Nc=512, K=1024
    gemm_bt<0, 0, 0><<<dim3(H_ / 128, T_ / 128), 256, 0, stream>>>(W2t, W1rm, nullptr, W12t, nullptr,
                                                                   H_, T_, H_, 0, 1.0f, 0.0f);
    // P2: W1ct = (W1a @ W1b)^T : A=W1bt, Bt=W1ab, M=512, Nc=1024, K=1024
    gemm_bt<0, 0, 0><<<dim3(T_ / 128, H_ / 128), 256, 0, stream>>>(W1bt, W1ab, nullptr, W1ct, nullptr,
                                                                   T_, H_, H_, 0, 1.0f, 0.0f);
    // P3: W2ct = (W2a @ W2b)^T : A=W2bt, Bt=W2ab, M=1024, Nc=256, K=256
    gemm_bt<0, 0, 0><<<dim3(H_ / 128, N_ / 128), 256, 0, stream>>>(W2bt, W2ab, nullptr, W2ct, nullptr,
                                                                   H_, N_, N_, 0, 1.0f, 0.0f);

    // --- main chain (3 big GEMMs) ---
    // GA: h2 = h @ W12 + t12         [32768,1024] K=512
    gemm256<0, 0><<<dim3(128 * 4), 512, 0, stream>>>(h_bf, W12t, nullptr, h2_bf, t12, H_, T_, 8, 2);
    // GB: q = sigma(h2 @ W1c), transposed write q[B,T,N]   K=1024
    gemm256<1, 2><<<dim3(128 * 2), 512, 0, stream>>>(h2_bf, W1ct, nullptr, q_bf, nullptr, T_, H_, 0, 1);
    // GC: out = sigma(q @ W2c) f32   [65536,1024] K=256
    gemm256<1, 1><<<dim3(256 * 4), 512, 0, stream>>>(q_bf, W2ct, out, nullptr, nullptr, H_, N_, 0, 2);
}

// Round 6
// 374.639 us; speedup vs baseline: 1.4432x; 1.2743x over previous
//
#include <hip/hip_runtime.h>
#include <hip/hip_bf16.h>

#define B_ 128
#define T_ 512
#define N_ 256
#define H_ 1024

typedef unsigned short u16;
typedef __attribute__((ext_vector_type(8))) __bf16 bf16x8;
typedef __attribute__((ext_vector_type(4))) float f32x4;

__device__ __forceinline__ u16 f2bf(float f) {
    unsigned u = __float_as_uint(f);
    u = (u + 0x7FFFu + ((u >> 16) & 1u)) >> 16;
    return (u16)u;
}

__device__ __forceinline__ void g2l16(const void* g, void* l) {
    __builtin_amdgcn_global_load_lds(
        (const __attribute__((address_space(1))) void*)g,
        (__attribute__((address_space(3))) void*)l,
        16, 0, 0);
}

// ===========================================================================
// 256x256-tile 8-wave phase-pipelined GEMM with counted vmcnt.
// R6: default unroll restored (A/B vs R5's `#pragma unroll 1`).
// OUT: 0 = bf16 row-major, 1 = f32 row-major, 2 = bf16 transposed q-write.
// ===========================================================================
#define LBUF 32768u
#define LMAT 16384u
#define LKS  8192u

#define BAR() { __builtin_amdgcn_s_barrier(); }
#define GATE(N) { asm volatile("s_waitcnt vmcnt(" #N ")" ::: "memory"); \
                  __builtin_amdgcn_s_barrier(); }
#define LD4(dst, base) { _Pragma("unroll") for (int i_ = 0; i_ < 4; ++i_) \
    dst[i_] = *(const bf16x8*)(L + (base) + i_ * 512); }
#define MF16(MB, RA, RB) { __builtin_amdgcn_s_setprio(1); \
    _Pragma("unroll") for (int mi_ = 0; mi_ < 4; ++mi_) \
    _Pragma("unroll") for (int ni_ = 0; ni_ < 4; ++ni_) \
        acc[(MB) + mi_][ni_] = __builtin_amdgcn_mfma_f32_16x16x32_bf16( \
            RA[mi_], RB[ni_], acc[(MB) + mi_][ni_], 0, 0, 0); \
    __builtin_amdgcn_s_setprio(0); }

template<int ACT, int OUT>
__global__ __launch_bounds__(512, 2) void gemm256(
    const u16* __restrict__ A, const u16* __restrict__ Bt,
    float* __restrict__ Cf, u16* __restrict__ Cb,
    const float* __restrict__ bias,
    int Nc, int K, int bshift, int gysh)
{
    __shared__ u16 L[65536];
    const int tid = threadIdx.x;
    const int wave = tid >> 6, lane = tid & 63;
    const int l16 = lane & 15, lh = lane >> 4;
    const int wm = wave >> 2, wn = wave & 3;

    const int qq = (int)gridDim.x >> 3;
    const int orig = (int)blockIdx.x;
    const int wg = (orig & 7) * qq + (orig >> 3);
    const int by = wg & ((1 << gysh) - 1), bx = wg >> gysh;
    const size_t m0 = (size_t)bx * 256, n0 = (size_t)by * 256;

    const int sx8 = (lh ^ ((l16 >> 1) & 3)) * 8;
    const unsigned aoff = (unsigned)(wm * 4096 + l16 * 32 + sx8);
    const unsigned boff = (unsigned)(LMAT + wn * 2048 + l16 * 32 + sx8);

    const int srow = tid >> 2;
    const int sslot = (tid & 3) ^ ((srow >> 1) & 3);
    const size_t jstr = (size_t)128 * K;
    const u16* gA = A + (m0 + srow) * (size_t)K + sslot * 8;
    const u16* gB = Bt + (n0 + srow) * (size_t)K + sslot * 8;
    u16* const dA0 = L + (unsigned)(wave * 512);
    u16* const dB0 = L + LMAT + (unsigned)(wave * 512);

    f32x4 acc[8][4] = {};
    const int nt = K >> 6;

    g2l16(gA, dA0);             g2l16(gA + jstr, dA0 + 4096);
    g2l16(gB, dB0);             g2l16(gB + jstr, dB0 + 4096);
    g2l16(gA + 32, dA0 + LKS);  g2l16(gA + 32 + jstr, dA0 + LKS + 4096);
    g2l16(gB + 32, dB0 + LKS);  g2l16(gB + 32 + jstr, dB0 + LKS + 4096);
    GATE(4);

    for (int t = 0; t < nt - 1; ++t) {
        const unsigned ab = (t & 1) ? LBUF : 0u;
        const unsigned an = ab ^ LBUF;
        const u16* gAt = gA + (size_t)(t + 1) * 64;
        const u16* gBt = gB + (size_t)(t + 1) * 64;
        bf16x8 ra[4], ra2[4], rb0r[4], rb1r[4];
        LD4(ra,   ab + aoff);
        LD4(rb0r, ab + boff);
        g2l16(gAt, dA0 + an);  g2l16(gAt + jstr, dA0 + an + 4096);
        BAR();
        MF16(0, ra, rb0r);
        BAR();
        LD4(ra2, ab + aoff + 2048);
        g2l16(gBt, dB0 + an);  g2l16(gBt + jstr, dB0 + an + 4096);
        BAR();
        MF16(4, ra2, rb0r);
        GATE(4);
        LD4(ra,   ab + LKS + aoff);
        LD4(rb1r, ab + LKS + boff);
        g2l16(gAt + 32, dA0 + an + LKS);  g2l16(gAt + 32 + jstr, dA0 + an + LKS + 4096);
        BAR();
        MF16(0, ra, rb1r);
        BAR();
        LD4(ra2, ab + LKS + aoff + 2048);
        g2l16(gBt + 32, dB0 + an + LKS);  g2l16(gBt + 32 + jstr, dB0 + an + LKS + 4096);
        BAR();
        MF16(4, ra2, rb1r);
        GATE(4);
    }

    {
        const unsigned ab = ((nt - 1) & 1) ? LBUF : 0u;
        bf16x8 ra[4], ra2[4], rb0r[4], rb1r[4];
        LD4(ra,   ab + aoff);
        LD4(rb0r, ab + boff);
        BAR();
        MF16(0, ra, rb0r);
        BAR();
        LD4(ra2, ab + aoff + 2048);
        BAR();
        MF16(4, ra2, rb0r);
        GATE(0);
        LD4(ra,   ab + LKS + aoff);
        LD4(rb1r, ab + LKS + boff);
        BAR();
        MF16(0, ra, rb1r);
        BAR();
        LD4(ra2, ab + LKS + aoff + 2048);
        BAR();
        MF16(4, ra2, rb1r);
    }

    const size_t NcS = (size_t)Nc;
#pragma unroll
    for (int mi = 0; mi < 8; ++mi) {
#pragma unroll
        for (int ni = 0; ni < 4; ++ni) {
            size_t rbase = m0 + wm * 128 + mi * 16 + lh * 4;
            size_t col   = n0 + wn * 64 + ni * 16 + l16;
            if (OUT == 2) {
                u16 e[4];
#pragma unroll
                for (int rr = 0; rr < 4; ++rr) {
                    float v = acc[mi][ni][rr];
                    v = 1.0f / (1.0f + __expf(-v));
                    e[rr] = f2bf(v);
                }
                size_t qi = ((rbase >> 8) * (size_t)T_ + col) * N_ + (rbase & 255);
                *(uint2*)(Cb + qi) = *(const uint2*)e;
            } else {
#pragma unroll
                for (int rr = 0; rr < 4; ++rr) {
                    size_t row = rbase + rr;
                    float v = acc[mi][ni][rr];
                    if (bias) v += bias[(row >> bshift) * NcS + col];
                    if (ACT) v = 1.0f / (1.0f + __expf(-v));
                    if (OUT == 1) Cf[row * NcS + col] = v;
                    else          Cb[row * NcS + col] = f2bf(v);
                }
            }
        }
    }
}

// ---------------------------------------------------------------------------
// 128x128 2-barrier GEMM body (device fn) for small GEMMs.
// outmode: 0 = bf16 Cb[row*Nc+col] (+bmul*bias[(row>>bshift)*Nc+col] if bias)
//          1 = f32  Cf[row*Nc+col] (+bias likewise)
//          2 = dual-concat bf16 Cb[row*Nc+col] + bias[col&1023]*(col<1024?1:256/255)
// ---------------------------------------------------------------------------
__device__ __forceinline__ void small_body(
    const u16* __restrict__ A, const u16* __restrict__ Bt,
    float* __restrict__ Cf, u16* __restrict__ Cb,
    const float* __restrict__ bias,
    int Nc, int K, int lda, int ldb, int outmode, int bshift,
    float kscale, float bmul, int bx, int by)
{
    __shared__ u16 lA[128 * 64];
    __shared__ u16 lB[128 * 64];
    const int tid = threadIdx.x;
    const int wave = tid >> 6, lane = tid & 63;
    const int l16 = lane & 15, lh = lane >> 4;
    const int wm = wave >> 1, wn = wave & 1;
    const long m0 = (long)bx * 128;
    const long n0 = (long)by * 128;

    f32x4 acc[4][4] = {};

    for (int k0 = 0; k0 < K; k0 += 64) {
#pragma unroll
        for (int j = 0; j < 4; ++j) {
            int c = j * 256 + tid;
            int row = c >> 3, col = (c & 7) << 3;
            g2l16(A  + (m0 + row) * (size_t)lda + k0 + col, &lA[(size_t)(j * 256 + (wave << 6)) * 8]);
            g2l16(Bt + (n0 + row) * (size_t)ldb + k0 + col, &lB[(size_t)(j * 256 + (wave << 6)) * 8]);
        }
        __syncthreads();
#pragma unroll
        for (int s = 0; s < 2; ++s) {
            bf16x8 af[4], bfr[4];
#pragma unroll
            for (int mi = 0; mi < 4; ++mi)
                af[mi] = *(const bf16x8*)&lA[((wm << 6) + (mi << 4) + l16) * 64 + s * 32 + (lh << 3)];
#pragma unroll
            for (int ni = 0; ni < 4; ++ni)
                bfr[ni] = *(const bf16x8*)&lB[((wn << 6) + (ni << 4) + l16) * 64 + s * 32 + (lh << 3)];
#pragma unroll
            for (int mi = 0; mi < 4; ++mi)
#pragma unroll
                for (int ni = 0; ni < 4; ++ni)
                    acc[mi][ni] = __builtin_amdgcn_mfma_f32_16x16x32_bf16(af[mi], bfr[ni], acc[mi][ni], 0, 0, 0);
        }
        __syncthreads();
    }

#pragma unroll
    for (int mi = 0; mi < 4; ++mi) {
#pragma unroll
        for (int ni = 0; ni < 4; ++ni) {
            long rbase = m0 + (wm << 6) + (mi << 4) + (lh << 2);
            long col   = n0 + (wn << 6) + (ni << 4) + l16;
#pragma unroll
            for (int r = 0; r < 4; ++r) {
                long row = rbase + r;
                float v = acc[mi][ni][r] * kscale;
                if (outmode == 2) {
                    v += (col < 1024 ? 1.0f : 256.0f / 255.0f) * bias[col & 1023];
                    Cb[(size_t)row * Nc + col] = f2bf(v);
                } else {
                    if (bias) v += bmul * bias[(size_t)(row >> bshift) * Nc + col];
                    if (outmode == 1) Cf[(size_t)row * Nc + col] = v;
                    else              Cb[(size_t)row * Nc + col] = f2bf(v);
                }
            }
        }
    }
}

// templated wrapper for the remaining standalone small GEMM (S23)
template<int OUTF32>
__global__ __launch_bounds__(256) void gemm_bt(
    const u16* __restrict__ A, const u16* __restrict__ Bt,
    float* __restrict__ Cf, u16* __restrict__ Cb,
    const float* __restrict__ bias,
    int Nc, int K, int bshift, float kscale, float bmul)
{
    small_body(A, Bt, Cf, Cb, bias, Nc, K, K, K, OUTF32, bshift, kscale, bmul,
               blockIdx.x, blockIdx.y);
}

// Four independent small GEMMs in one launch (96 blocks):
//  0-31:  P1  W12t = (W1'@W2')^T      A=W2cat(lda2048) Bt=W1rm   M=1024 Nc=512  K=1024
// 32-63:  P2  W1ct = (W1a@W1b)^T      A=W1bt           Bt=W1ab   M=512  Nc=1024 K=1024
// 64-79:  P3  W2ct = (W2a@W2b)^T      A=W2bt           Bt=W2ab   M=1024 Nc=256  K=256
// 80-95:  S1  Acat = s1@[Wl1|Wl1+Wr1]/255 (+b1 terms)  dual bf16 M=128  Nc=2048 K=512
__global__ __launch_bounds__(256) void k_small4(
    const u16* __restrict__ W2cat, const u16* __restrict__ W1rm, u16* __restrict__ W12t,
    const u16* __restrict__ W1bt, const u16* __restrict__ W1ab, u16* __restrict__ W1ct,
    const u16* __restrict__ W2bt, const u16* __restrict__ W2ab, u16* __restrict__ W2ct,
    const u16* __restrict__ s1b, const u16* __restrict__ Wcat, u16* __restrict__ Acat,
    const float* __restrict__ b1)
{
    const int bid = blockIdx.x;
    if (bid < 32) {
        small_body(W2cat, W1rm, nullptr, W12t, nullptr, 512, 1024, 2048, 1024,
                   0, 0, 1.0f, 0.0f, bid >> 2, bid & 3);
    } else if (bid < 64) {
        int r = bid - 32;
        small_body(W1bt, W1ab, nullptr, W1ct, nullptr, 1024, 1024, 1024, 1024,
                   0, 0, 1.0f, 0.0f, r >> 3, r & 7);
    } else if (bid < 80) {
        int r = bid - 64;
        small_body(W2bt, W2ab, nullptr, W2ct, nullptr, 256, 256, 256, 256,
                   0, 0, 1.0f, 0.0f, r >> 1, r & 1);
    } else {
        int r = bid - 80;
        small_body(s1b, Wcat, nullptr, Acat, b1, 2048, 512, 512, 512,
                   2, 0, 1.0f / 255.0f, 0.0f, 0, r);
    }
}

// x[B,T,N] f32 -> h[B,N,T] bf16 transpose + per-(b,t) rowsum (one x read)
__global__ __launch_bounds__(256) void k_trx_rs(
    const float* __restrict__ x, u16* __restrict__ h, u16* __restrict__ s1b)
{
    __shared__ float sm[32][257];
    const int b = blockIdx.y, t0 = blockIdx.x * 32;
    const int tid = threadIdx.x;
    const float* xb = x + ((size_t)b * T_ + t0) * N_;
#pragma unroll 8
    for (int j = 0; j < 32; ++j)
        sm[j][tid] = xb[(size_t)j * N_ + tid];
    __syncthreads();
    const int wave = tid >> 6, lane = tid & 63;
#pragma unroll
    for (int i = 0; i < 8; ++i) {
        int j = wave * 8 + i;
        float s = sm[j][lane] + sm[j][lane + 64] + sm[j][lane + 128] + sm[j][lane + 192];
#pragma unroll
        for (int o = 32; o; o >>= 1) s += __shfl_down(s, o, 64);
        if (lane == 0) s1b[(size_t)b * T_ + t0 + j] = f2bf(s);
    }
    u16 e[32];
#pragma unroll
    for (int j = 0; j < 32; ++j) e[j] = f2bf(sm[j][tid]);
    uint4* dst = (uint4*)(h + ((size_t)b * N_ + tid) * T_ + t0);
    const uint4* src = (const uint4*)e;
#pragma unroll
    for (int v = 0; v < 4; ++v) dst[v] = src[v];
}

// All weight transforms in one launch (2848 blocks of (32,8)):
//    0- 511  A: Wl1,Wr1[512,1024] -> Wcat[c][r] (c<1024: Wl1; else Wl1+Wr1), W1rm[r][c]=wr-wl/255
//  512-1535  B: Wl2,Wr2[1024,1024] -> W2cat[c][0..1023]=wr-wl/255 ^T, W2cat[c][1024+r]=Wl2^T
// 1536-2047  C: W1b[1024,512] -> W1bt[512,1024]
// 2048-2303  D: W2b[256,1024] -> W2bt[1024,256]
// 2304-2847  E: f32->bf16 casts of W1a then W2a (linear, 8 elems/thread)
__global__ void k_wtr(const float* __restrict__ Wl1, const float* __restrict__ Wr1,
                      const float* __restrict__ Wl2, const float* __restrict__ Wr2,
                      const float* __restrict__ W1b, const float* __restrict__ W2b,
                      const float* __restrict__ W1a, const float* __restrict__ W2a,
                      u16* __restrict__ Wcat, u16* __restrict__ W1rm,
                      u16* __restrict__ W2cat,
                      u16* __restrict__ W1bt, u16* __restrict__ W2bt,
                      u16* __restrict__ W1ab, u16* __restrict__ W2ab)
{
    __shared__ float tl[32][33], tr[32][33];
    int bid = blockIdx.x;
    const int tx = threadIdx.x, ty = threadIdx.y;
    if (bid < 512) {
        int r0 = (bid >> 5) * 32, c0 = (bid & 31) * 32;
#pragma unroll
        for (int i = 0; i < 4; ++i) {
            int r = r0 + ty + 8 * i;
            float wl = Wl1[(size_t)r * H_ + c0 + tx];
            float wr = Wr1[(size_t)r * H_ + c0 + tx];
            tl[ty + 8 * i][tx] = wl;
            tr[ty + 8 * i][tx] = wl + wr;
            W1rm[(size_t)r * H_ + c0 + tx] = f2bf(wr - wl * (1.0f / 255.0f));
        }
        __syncthreads();
#pragma unroll
        for (int i = 0; i < 4; ++i) {
            size_t o = (size_t)(c0 + ty + 8 * i) * T_ + r0 + tx;
            Wcat[o]                       = f2bf(tl[tx][ty + 8 * i]);
            Wcat[o + (size_t)1024 * T_]   = f2bf(tr[tx][ty + 8 * i]);
        }
    } else if (bid < 1536) {
        bid -= 512;
        int r0 = (bid >> 5) * 32, c0 = (bid & 31) * 32;
#pragma unroll
        for (int i = 0; i < 4; ++i) {
            int r = r0 + ty + 8 * i;
            float wl = Wl2[(size_t)r * H_ + c0 + tx];
            float wr = Wr2[(size_t)r * H_ + c0 + tx];
            tl[ty + 8 * i][tx] = wr - wl * (1.0f / 255.0f);
            tr[ty + 8 * i][tx] = wl;
        }
        __syncthreads();
#pragma unroll
        for (int i = 0; i < 4; ++i) {
            size_t o = (size_t)(c0 + ty + 8 * i) * 2048 + r0 + tx;
            W2cat[o]        = f2bf(tl[tx][ty + 8 * i]);
            W2cat[o + 1024] = f2bf(tr[tx][ty + 8 * i]);
        }
    } else if (bid < 2048) {
        bid -= 1536;
        int r0 = (bid >> 4) * 32, c0 = (bid & 15) * 32;
#pragma unroll
        for (int i = 0; i < 4; ++i)
            tl[ty + 8 * i][tx] = W1b[(size_t)(r0 + ty + 8 * i) * T_ + c0 + tx];
        __syncthreads();
#pragma unroll
        for (int i = 0; i < 4; ++i)
            W1bt[(size_t)(c0 + ty + 8 * i) * H_ + r0 + tx] = f2bf(tl[tx][ty + 8 * i]);
    } else if (bid < 2304) {
        bid -= 2048;
        int r0 = (bid >> 5) * 32, c0 = (bid & 31) * 32;
#pragma unroll
        for (int i = 0; i < 4; ++i)
            tl[ty + 8 * i][tx] = W2b[(size_t)(r0 + ty + 8 * i) * H_ + c0 + tx];
        __syncthreads();
#pragma unroll
        for (int i = 0; i < 4; ++i)
            W2bt[(size_t)(c0 + ty + 8 * i) * N_ + r0 + tx] = f2bf(tl[tx][ty + 8 * i]);
    } else {
        int i = (bid - 2304) * 256 + ty * 32 + tx;
        const int n1 = H_ * H_ / 8;
        const float* s; u16* d;
        if (i < n1) { s = W1a; d = W1ab; }
        else        { s = W2a; d = W2ab; i -= n1; }
        float4 a = ((const float4*)s)[2 * i], b = ((const float4*)s)[2 * i + 1];
        u16 e[8] = {f2bf(a.x), f2bf(a.y), f2bf(a.z), f2bf(a.w),
                    f2bf(b.x), f2bf(b.y), f2bf(b.z), f2bf(b.w)};
        ((uint4*)d)[i] = *(const uint4*)e;
    }
}

extern "C" void kernel_launch(void* const* d_in, const int* in_sizes, int n_in,
                              void* d_out, int out_size, void* d_ws, size_t ws_size,
                              hipStream_t stream)
{
    const float* x   = (const float*)d_in[0];
    const float* Wl1 = (const float*)d_in[1];
    const float* Wr1 = (const float*)d_in[2];
    const float* b1  = (const float*)d_in[3];
    const float* Wl2 = (const float*)d_in[4];
    const float* Wr2 = (const float*)d_in[5];
    const float* b2  = (const float*)d_in[6];
    const float* W1a = (const float*)d_in[7];
    const float* W1b = (const float*)d_in[8];
    const float* W2a = (const float*)d_in[9];
    const float* W2b = (const float*)d_in[10];
    float* out = (float*)d_out;

    char* ws = (char*)d_ws;
    size_t off = 0;
    auto alloc = [&](size_t bytes) -> char* {
        char* p = ws + off;
        off += (bytes + 255) & ~(size_t)255;
        return p;
    };

    const size_t BN = (size_t)B_ * N_;   // 32768
    const size_t BT = (size_t)B_ * T_;   // 65536

    u16* h_bf   = (u16*)alloc(BN * T_ * 2);              // h, later q
    u16* h2_bf  = (u16*)alloc(BN * H_ * 2);
    u16* Wcat   = (u16*)alloc((size_t)2048 * T_ * 2);    // [Wl1t ; Wlr1t] as [2048][512]
    u16* W1rm   = (u16*)alloc((size_t)T_ * H_ * 2);
    u16* W2cat  = (u16*)alloc((size_t)H_ * 2048 * 2);    // [1024][2048] = [W2'^T | Wl2^T]
    u16* W1bt   = (u16*)alloc((size_t)T_ * H_ * 2);
    u16* W1ab   = (u16*)alloc((size_t)H_ * H_ * 2);
    u16* W1ct   = (u16*)alloc((size_t)T_ * H_ * 2);
    u16* W2bt   = (u16*)alloc((size_t)H_ * N_ * 2);
    u16* W2ab   = (u16*)alloc((size_t)N_ * N_ * 2);
    u16* W2ct   = (u16*)alloc((size_t)H_ * N_ * 2);
    u16* W12t   = (u16*)alloc((size_t)H_ * T_ * 2);
    u16* s1b    = (u16*)alloc(BT * 2);
    u16* Acat   = (u16*)alloc((size_t)B_ * 2048 * 2);    // [t1b1 | u1s]
    float* t12  = (float*)alloc((size_t)B_ * H_ * 4);

    u16* q_bf = h_bf;

    // --- prep (3 launches) ---
    k_wtr<<<dim3(2848), dim3(32, 8), 0, stream>>>(Wl1, Wr1, Wl2, Wr2, W1b, W2b, W1a, W2a,
                                                  Wcat, W1rm, W2cat, W1bt, W2bt, W1ab, W2ab);
    k_trx_rs<<<dim3(T_ / 32, B_), 256, 0, stream>>>(x, h_bf, s1b);
    k_small4<<<dim3(96), 256, 0, stream>>>(W2cat, W1rm, W12t, W1bt, W1ab, W1ct,
                                           W2bt, W2ab, W2ct, s1b, Wcat, Acat, b1);
    // S23: t12 = [t1b1|u1s] @ [W2'^T|Wl2^T]^T + b2   (K=2048)
    gemm_bt<1><<<dim3(1, H_ / 128), 256, 0, stream>>>(Acat, W2cat, t12, nullptr, b2,
                                                      H_, 2048, 31, 1.0f, 1.0f);

    // --- main chain (3 big GEMMs) ---
    gemm256<0, 0><<<dim3(128 * 4), 512, 0, stream>>>(h_bf, W12t, nullptr, h2_bf, t12, H_, T_, 8, 2);
    gemm256<1, 2><<<dim3(128 * 2), 512, 0, stream>>>(h2_bf, W1ct, nullptr, q_bf, nullptr, T_, H_, 0, 1);
    gemm256<1, 1><<<dim3(256 * 4), 512, 0, stream>>>(q_bf, W2ct, out, nullptr, nullptr, H_, N_, 0, 2);
}